// Round 12
// baseline (885.243 us; speedup 1.0000x reference)
//
#include <hip/hip_runtime.h>
#include <hip/hip_bf16.h>

#define NPTS 8192
#define DIM 32
#define KKDE 32
#define KRIPS 16
#define DESTNUM 10

__device__ __forceinline__ unsigned long long shfl_xor_u64(unsigned long long v, int m) {
  int lo = __shfl_xor((int)(unsigned)(v & 0xFFFFFFFFull), m, 64);
  int hi = __shfl_xor((int)(unsigned)(v >> 32), m, 64);
  return (((unsigned long long)(unsigned)hi) << 32) | (unsigned)lo;
}

// DPP row (16-lane) rotate-based reductions: VALU-speed.
template <int CTRL>
__device__ __forceinline__ int dpp_mov(int v) {
  return __builtin_amdgcn_update_dpp(0, v, CTRL, 0xF, 0xF, false);
}
__device__ __forceinline__ int row_max16(int v) {
  int t;
  t = dpp_mov<0x128>(v); v = (t > v) ? t : v;  // row_ror:8
  t = dpp_mov<0x124>(v); v = (t > v) ? t : v;  // row_ror:4
  t = dpp_mov<0x122>(v); v = (t > v) ? t : v;  // row_ror:2
  t = dpp_mov<0x121>(v); v = (t > v) ? t : v;  // row_ror:1
  return v;
}
__device__ __forceinline__ int row_min16(int v) {
  int t;
  t = dpp_mov<0x128>(v); v = (t < v) ? t : v;
  t = dpp_mov<0x124>(v); v = (t < v) ? t : v;
  t = dpp_mov<0x122>(v); v = (t < v) ? t : v;
  t = dpp_mov<0x121>(v); v = (t < v) ? t : v;
  return v;
}
// 64-lane sum: DPP row-sum then 4 readlanes (uniform result, no ds_swizzle chain)
__device__ __forceinline__ int wave_sum64(int c) {
  int t;
  t = dpp_mov<0x128>(c); c += t;
  t = dpp_mov<0x124>(c); c += t;
  t = dpp_mov<0x122>(c); c += t;
  t = dpp_mov<0x121>(c); c += t;
  return __builtin_amdgcn_readlane(c, 0) + __builtin_amdgcn_readlane(c, 16) +
         __builtin_amdgcn_readlane(c, 32) + __builtin_amdgcn_readlane(c, 48);
}

// ---------------- dtype detector: is x bf16-packed or f32? ----------------
__global__ __launch_bounds__(64) void detect_kernel(const unsigned short* __restrict__ x,
                                                    int* __restrict__ flag) {
  int lane = threadIdx.x;
  unsigned u = x[2 * lane];
  int e = (u >> 7) & 0xFF;
  bool pass = (e >= 110 && e <= 130);
  unsigned long long b = __ballot(pass);
  if (lane == 0) flag[0] = (__popcll(b) >= 32) ? 1 : 0;
}

// ---------------- transpose: xT[q][p] = x[p][q] as f32 (exact) ----------------
__global__ __launch_bounds__(256) void tr_kernel(const unsigned short* __restrict__ xh,
                                                 const int* __restrict__ flag,
                                                 float* __restrict__ xT) {
  int e = blockIdx.x * 256 + threadIdx.x;  // < NPTS*DIM
  if (e >= NPTS * DIM) return;
  int p = e >> 5, q = e & 31;
  float v;
  if (flag[0] != 0) v = __uint_as_float(((unsigned)xh[e]) << 16);
  else v = ((const float*)xh)[e];
  xT[q * NPTS + p] = v;
}

// ---------------- shared register-resident per-wave top-K selection ----------------
// v8: data-seeded bisection bracket (R9-proven). Output bit-identical for any
// final hi with count in [32,64] (candidates superset of true top-32).
__device__ __forceinline__ void topk_emit(const unsigned* K, const int i, const int w,
                                          const int lane, const int t,
                                          unsigned long long* cand, unsigned long long* srt,
                                          unsigned long long* fin, float* knnv, int* knni,
                                          float* __restrict__ kde, int* __restrict__ rips) {
  unsigned lmin = K[0];
#pragma unroll
  for (int e = 1; e < 32; ++e) lmin = (K[e] < lmin) ? K[e] : lmin;
  // all values < 0x80000000 -> int compare == uint compare
  const int rmn = row_min16((int)lmin);
  const int rmx = row_max16((int)lmin);
  int gmn = __builtin_amdgcn_readlane(rmn, 0);
  int a16 = __builtin_amdgcn_readlane(rmn, 16); gmn = (a16 < gmn) ? a16 : gmn;
  int a32 = __builtin_amdgcn_readlane(rmn, 32); gmn = (a32 < gmn) ? a32 : gmn;
  int a48 = __builtin_amdgcn_readlane(rmn, 48); gmn = (a48 < gmn) ? a48 : gmn;
  int gmx = __builtin_amdgcn_readlane(rmx, 0);
  int b16 = __builtin_amdgcn_readlane(rmx, 16); gmx = (b16 > gmx) ? b16 : gmx;
  int b32 = __builtin_amdgcn_readlane(rmx, 32); gmx = (b32 > gmx) ? b32 : gmx;
  int b48 = __builtin_amdgcn_readlane(rmx, 48); gmx = (b48 > gmx) ? b48 : gmx;
  unsigned lo = (gmn == 0) ? 0u : (unsigned)gmn - 1u;
  unsigned hi = (unsigned)gmx;
  int chi = 2048;
  while (chi > 64 && (hi - lo) > 3u) {
    const unsigned span = hi - lo;
    const unsigned t1 = lo + (span >> 2);
    const unsigned t2 = lo + (span >> 1);
    int c = 0;
#pragma unroll
    for (int e = 0; e < 32; ++e) {
      unsigned a = (K[e] <= t2) ? 0x10000u : 0u;
      a = (K[e] <= t1) ? 0x10001u : a;
      c += (int)a;
    }
    const int tot = wave_sum64(c);
    const int c1 = tot & 0xFFFF;
    const int c2 = (int)((unsigned)tot >> 16);
    if (c1 >= 32) { hi = t1; chi = c1; }
    else if (c2 >= 32) { lo = t1; hi = t2; chi = c2; }
    else lo = t2;
  }
  while (chi > 64 && (hi - lo) > 1u) {  // exact tail (pathological ties only)
    const unsigned mid = lo + ((hi - lo) >> 1);
    int c = 0;
#pragma unroll
    for (int e = 0; e < 32; ++e) c += (K[e] <= mid) ? 1 : 0;
    const int tot = wave_sum64(c);
    if (tot >= 32) { hi = mid; chi = tot; } else lo = mid;
  }
  // deterministic extraction: ballot + prefix popcount
  cand[(w << 6) | lane] = ~0ull;
  const unsigned long long below = (lane == 0) ? 0ull : (~0ull >> (64 - lane));
  int base = 0;
#pragma unroll
  for (int e = 0; e < 32; ++e) {
    const bool sel = (K[e] <= hi);
    const unsigned long long b = __ballot(sel);
    if (sel) {
      const int pos = base + __popcll(b & below);
      if (pos < 64) {
        const int col = ((((w << 9) + ((e >> 2) << 6) + lane)) << 2) + (e & 3);
        cand[(w << 6) + pos] = (((unsigned long long)K[e]) << 32) | (unsigned)col;
      }
    }
    base += __popcll(b);
  }
  // per-wave bitonic sort of 64 candidates (v5 verbatim)
  unsigned long long v = cand[(w << 6) | lane];
#pragma unroll
  for (int k = 2; k <= 64; k <<= 1) {
#pragma unroll
    for (int j = 32; j > 0; j >>= 1) {
      if (j >= k) continue;
      unsigned long long o = shfl_xor_u64(v, j);
      bool keepMin = (((lane & k) == 0) == ((lane & j) == 0));
      v = keepMin ? (v < o ? v : o) : (v > o ? v : o);
    }
  }
  if (lane < 32) srt[(w << 5) | lane] = v;
  __syncthreads();
  if (w < 2) {
    const unsigned long long* A = &srt[(w * 2) << 5];
    const unsigned long long* B = &srt[(w * 2 + 1) << 5];
    unsigned long long m = (lane < 32) ? A[lane] : B[63 - lane];
#pragma unroll
    for (int j = 32; j > 0; j >>= 1) {
      unsigned long long o = shfl_xor_u64(m, j);
      bool keepMin = ((lane & j) == 0);
      m = keepMin ? (m < o ? m : o) : (m > o ? m : o);
    }
    if (lane < 32) fin[(w << 5) | lane] = m;
  }
  __syncthreads();
  if (w == 0) {
    unsigned long long m = (lane < 32) ? fin[lane] : fin[32 + (63 - lane)];
#pragma unroll
    for (int j = 32; j > 0; j >>= 1) {
      unsigned long long o = shfl_xor_u64(m, j);
      bool keepMin = ((lane & j) == 0);
      m = keepMin ? (m < o ? m : o) : (m > o ? m : o);
    }
    if (lane < 32) {
      knnv[lane] = __uint_as_float((unsigned)(m >> 32));
      knni[lane] = (int)(m & 0x1FFFull);
    }
  }
  __syncthreads();
  if (t == 0) {
    float s = 0.f;
    for (int k = 0; k < KKDE; ++k) s += expf(knnv[k] * -0.015625f);  // exp(-d2/64), ascending
    kde[i] = s;
  }
  if (t < KRIPS) rips[i * KRIPS + t] = knni[t];
}

// ---------------- kNN v10: fused QB=2, K-arrays in registers, xi in LDS ----------------
// R10's QB=2 spilled because KA+KB+xiA+xiB = 128 VGPRs of arrays. Fix: queries
// live ONLY in LDS (float2 xis2[32], broadcast ds_read_b64 per q), halving array
// pressure to KA+KB = 64. The per-iteration __syncthreads() in the s-loop is a
// deliberate LDS fence: it stops LICM from hoisting the 32 xis2 loads out of the
// loop (which would recreate the 64-VGPR xi arrays and re-spill).
// Each thread's float4 column-load feeds BOTH queries' fmaf chains -> L2 read
// traffic halves vs QB=1 (8.6 GB -> 4.3 GB). Per-element arithmetic bitwise-
// identical to v5/v8 (ascending-q fmaf dot, shared col-norm chain,
// fmaxf(fmaf(-2,d,sq+s),0); diagonal exact-0 per query: column load is bitwise
// == the LDS-staged query, so dot==sq==s and fmaf(-2,d,2d)==0 exactly).
// topk_emit x2 sequentially: barrier structure race-checked (R2 run, absmax 0).
__global__ __launch_bounds__(256, 2) void knn2_kernel(const float* __restrict__ xT,
                                                      float* __restrict__ kde,
                                                      int* __restrict__ rips) {
  __shared__ unsigned long long cand[4 * 64];
  __shared__ unsigned long long srt[4 * 32];
  __shared__ unsigned long long fin[64];
  __shared__ float knnv[KKDE];
  __shared__ int knni[KKDE];
  __shared__ float2 xis2[DIM];  // xis2[q] = {xA[q], xB[q]}
  const int i0 = blockIdx.x * 2;
  const int t = threadIdx.x;
  const int w = t >> 6, lane = t & 63;
  if (t < DIM) {
    float a = xT[t * NPTS + i0];
    float b = xT[t * NPTS + i0 + 1];
    xis2[t] = make_float2(a, b);
  }
  __syncthreads();
  float sqA = 0.f, sqB = 0.f;
#pragma unroll
  for (int q = 0; q < DIM; ++q) {
    float2 ab = xis2[q];
    sqA = fmaf(ab.x, ab.x, sqA);
    sqB = fmaf(ab.y, ab.y, sqB);
  }
  const float4* xT4 = (const float4*)xT;
  unsigned KA[32], KB[32];
#pragma unroll
  for (int s = 0; s < 8; ++s) {
    __syncthreads();  // LDS fence: keep xis2 loads inside the loop (anti-LICM)
    const int j4 = (w << 9) + (s << 6) + lane;
    float a0 = 0.f, a1 = 0.f, a2 = 0.f, a3 = 0.f;
    float b0 = 0.f, b1 = 0.f, b2 = 0.f, b3 = 0.f;
    float s0 = 0.f, s1 = 0.f, s2 = 0.f, s3 = 0.f;
#pragma unroll
    for (int q = 0; q < DIM; ++q) {
      float4 v = xT4[q * (NPTS / 4) + j4];
      float2 ab = xis2[q];
      s0 = fmaf(v.x, v.x, s0); s1 = fmaf(v.y, v.y, s1);
      s2 = fmaf(v.z, v.z, s2); s3 = fmaf(v.w, v.w, s3);
      a0 = fmaf(ab.x, v.x, a0); a1 = fmaf(ab.x, v.y, a1);
      a2 = fmaf(ab.x, v.z, a2); a3 = fmaf(ab.x, v.w, a3);
      b0 = fmaf(ab.y, v.x, b0); b1 = fmaf(ab.y, v.y, b1);
      b2 = fmaf(ab.y, v.z, b2); b3 = fmaf(ab.y, v.w, b3);
    }
    KA[4 * s + 0] = __float_as_uint(fmaxf(fmaf(-2.f, a0, sqA + s0), 0.f));
    KA[4 * s + 1] = __float_as_uint(fmaxf(fmaf(-2.f, a1, sqA + s1), 0.f));
    KA[4 * s + 2] = __float_as_uint(fmaxf(fmaf(-2.f, a2, sqA + s2), 0.f));
    KA[4 * s + 3] = __float_as_uint(fmaxf(fmaf(-2.f, a3, sqA + s3), 0.f));
    KB[4 * s + 0] = __float_as_uint(fmaxf(fmaf(-2.f, b0, sqB + s0), 0.f));
    KB[4 * s + 1] = __float_as_uint(fmaxf(fmaf(-2.f, b1, sqB + s1), 0.f));
    KB[4 * s + 2] = __float_as_uint(fmaxf(fmaf(-2.f, b2, sqB + s2), 0.f));
    KB[4 * s + 3] = __float_as_uint(fmaxf(fmaf(-2.f, b3, sqB + s3), 0.f));
  }
  __syncthreads();
  topk_emit(KA, i0, w, lane, t, cand, srt, fin, knnv, knni, kde, rips);
  topk_emit(KB, i0 + 1, w, lane, t, cand, srt, fin, knnv, knni, kde, rips);
}

// ---------------- prep (1024 threads): fused max + normalize + death-init + argmin ----------------
__global__ __launch_bounds__(1024) void prep_kernel(float* __restrict__ kde,
                                                    int* __restrict__ death,
                                                    int* __restrict__ scali) {
  __shared__ float red[1024];
  __shared__ unsigned long long red64[1024];
  __shared__ float kmaxS;
  const int t = threadIdx.x;
  float m = 0.f;
  for (int p = t; p < NPTS; p += 1024) m = fmaxf(m, kde[p]);
  red[t] = m;
  __syncthreads();
  for (int s = 512; s; s >>= 1) {
    if (t < s) red[t] = fmaxf(red[t], red[t + s]);
    __syncthreads();
  }
  if (t == 0) kmaxS = red[0];
  __syncthreads();
  const float km = kmaxS;
  unsigned long long best = ~0ull;
  for (int p = t; p < NPTS; p += 1024) {
    float v = kde[p] / km;
    kde[p] = v;
    death[p] = -1;
    unsigned long long kk = (((unsigned long long)__float_as_uint(v)) << 32) | (unsigned)p;
    if (kk < best) best = kk;
  }
  red64[t] = best;
  __syncthreads();
  for (int s = 512; s; s >>= 1) {
    if (t < s && red64[t + s] < red64[t]) red64[t] = red64[t + s];
    __syncthreads();
  }
  if (t == 0) scali[0] = (int)(red64[0] & 0xFFFFFFFFull);
}

// ---------------- bitonic sort (1024 threads: R6-proven big win) ----------------
__global__ __launch_bounds__(1024) void sort_kernel(const float* __restrict__ kde,
                                                    int* __restrict__ order,
                                                    int* __restrict__ rankp) {
  __shared__ float kv[NPTS];            // 32 KB
  __shared__ unsigned short ki[NPTS];   // 16 KB
  int t = threadIdx.x;
  for (int p = t; p < NPTS; p += 1024) { kv[p] = kde[p]; ki[p] = (unsigned short)p; }
  __syncthreads();
  for (int size = 2; size <= NPTS; size <<= 1) {
    for (int stride = size >> 1; stride > 0; stride >>= 1) {
      for (int q = t; q < NPTS / 2; q += 1024) {
        int lo = ((q & ~(stride - 1)) << 1) | (q & (stride - 1));
        int hi = lo + stride;
        float va = kv[lo], vb = kv[hi];
        int ia = ki[lo], ib = ki[hi];
        bool aFirst = (va > vb) || (va == vb && ia < ib);
        bool up = ((lo & size) == 0);
        if (up != aFirst) {
          kv[lo] = vb; kv[hi] = va;
          ki[lo] = (unsigned short)ib; ki[hi] = (unsigned short)ia;
        }
      }
      __syncthreads();
    }
  }
  for (int p = t; p < NPTS; p += 1024) {
    int idx = ki[p];
    order[p] = idx;
    rankp[idx] = p;
  }
}

// ---------------- ordered neighbor stream (flat: [t*16 + kk]) ----------------
__global__ __launch_bounds__(256) void onbr_kernel(const int* __restrict__ order,
                                                   const int* __restrict__ rankp,
                                                   const int* __restrict__ rips,
                                                   unsigned short* __restrict__ onbr) {
  int e = blockIdx.x * 256 + threadIdx.x;  // e < NPTS*KRIPS
  if (e >= NPTS * KRIPS) return;
  int t = e >> 4, kk = e & 15;
  int i = order[t];
  int nbr = rips[i * KRIPS + kk];
  int r = rankp[nbr];
  unsigned short v = (unsigned short)r;
  if (r < t) {  // self has rank == t -> invalid, matching ref
    v |= 0x8000;
    if ((r >> 4) == (t >> 4)) v |= 0x4000;  // hazard: same prefetch window
  }
  onbr[e] = v;
}

// ---------------- persistence scan (R7 version, 426us best measured) ----------------
__global__ __launch_bounds__(64) void scan_kernel(const int* __restrict__ order,
                                                  const unsigned short* __restrict__ onbr,
                                                  int* __restrict__ death,
                                                  const int* __restrict__ scali) {
  __shared__ __align__(16) unsigned short rootR[NPTS];   // 16 KB, rank -> root rank
  __shared__ unsigned short orderS[NPTS];                // 16 KB, rank -> point id
  const int lane = threadIdx.x;
  for (int p = lane; p < NPTS; p += 64) {
    rootR[p] = (unsigned short)p;
    orderS[p] = (unsigned short)order[p];
  }
  __syncthreads();
  const int sub = lane >> 4;  // subgroup = DPP row = one position per call

  auto process = [&](unsigned short D, int pref, int posBase, bool& cln) {
    const int nbr = D & 0x1FFF;
    const bool valid = (D & 0x8000) != 0;
    const bool hz = (D & 0x4000) != 0;
    int rd = cln ? pref : (int)rootR[nbr];
    const int rv = row_max16(valid ? rd : -1);
    const bool uniOk = !valid || (rd == rv);
    const unsigned long long uniB = __ballot(uniOk);
    const unsigned long long hzB = __ballot(hz);
    const unsigned long long badB = (~uniB) | hzB;
    if (badB == 0ull) {  // all 4 rows uniform, no hazards: pure attach
      if ((lane & 15) == 0 && rv >= 0) rootR[posBase + sub] = (unsigned short)rv;
      return;
    }
    const int sstar = (__ffsll(badB) - 1) >> 4;  // first dirty row
    // rows < sstar are hazard-free & uniform: commit their attaches now
    if ((lane & 15) == 0 && sub < sstar && rv >= 0)
      rootR[posBase + sub] = (unsigned short)rv;
    cln = false;
    // hazard lanes may hold stale values; re-read them AFTER the commits above.
    if (hzB != 0ull) {
      const int f = (int)rootR[nbr];
      rd = hz ? f : rd;
    }
    // ---- exit ramp: hazard-patched batch that is still a pure attach ----
    {
      const bool fwd2 = hz && (nbr >= posBase + sstar);  // target not committed yet
      const int rv2 = row_max16(valid ? rd : -1);
      const unsigned long long bad2 = __ballot(fwd2 || (valid && rd != rv2));
      if (bad2 == 0ull) {
        if ((lane & 15) == 0 && sub >= sstar && rv2 >= 0)
          rootR[posBase + sub] = (unsigned short)rv2;
        return;
      }
    }
    const unsigned long long vbAll = __ballot(valid);
    for (int s = sstar; s < 4; ++s) {
      const int pos = posBase + s;
      const unsigned long long smask = 0xFFFFull << (s << 4);
      const unsigned long long vb = vbAll & smask;
      if (vb == 0ull) continue;  // birth: rootR[pos] stays pos
      const int cl = __ffsll(vb) - 1;
      const int gc = __builtin_amdgcn_readlane(rd, cl);
      const unsigned long long uni2 = __ballot(!valid || rd == gc);
      if ((uni2 & smask) == smask) {  // all valid roots equal: attach
        if (lane == (s << 4)) rootR[pos] = (unsigned short)gc;
        if (nbr == pos) rd = gc;
      } else {                        // merge: winner = min rank (densest)
        const int g = __builtin_amdgcn_readlane(row_min16(valid ? rd : 0x7FFFFFFF), s << 4);
        const bool dy = (sub == s) && valid && (rd != g);
        if (dy) {
          const int pid = orderS[rd];
          rootR[rd] = (unsigned short)g;
          death[pid] = (int)orderS[pos];
        }
        if (lane == (s << 4)) rootR[pos] = (unsigned short)g;
        unsigned long long db = __ballot(dy);
        if (nbr == pos) rd = g;
        while (db != 0ull) {
          const int dl = __ffsll(db) - 1;
          const int rcX = __builtin_amdgcn_readlane(rd, dl);
          db &= ~__ballot(rd == rcX);
          // members of rcX all lie in (rcX, pos): 8x-wide span relabel.
          {
            const int c0 = (rcX + 1) >> 3;   // first uint4 chunk (8 u16 each)
            const int c1 = (pos + 7) >> 3;   // exclusive
            uint4* root4 = (uint4*)rootR;
            const unsigned rc = (unsigned)rcX;
            const unsigned gg = (unsigned)g;
            for (int c = c0 + lane; c < c1; c += 64) {
              uint4 vv = root4[c];
              unsigned w0, w1;
              bool hit = false;
              w0 = vv.x & 0xFFFFu; w1 = vv.x >> 16;
              hit |= (w0 == rc) | (w1 == rc);
              w0 = (w0 == rc) ? gg : w0; w1 = (w1 == rc) ? gg : w1;
              vv.x = w0 | (w1 << 16);
              w0 = vv.y & 0xFFFFu; w1 = vv.y >> 16;
              hit |= (w0 == rc) | (w1 == rc);
              w0 = (w0 == rc) ? gg : w0; w1 = (w1 == rc) ? gg : w1;
              vv.y = w0 | (w1 << 16);
              w0 = vv.z & 0xFFFFu; w1 = vv.z >> 16;
              hit |= (w0 == rc) | (w1 == rc);
              w0 = (w0 == rc) ? gg : w0; w1 = (w1 == rc) ? gg : w1;
              vv.z = w0 | (w1 << 16);
              w0 = vv.w & 0xFFFFu; w1 = vv.w >> 16;
              hit |= (w0 == rc) | (w1 == rc);
              w0 = (w0 == rc) ? gg : w0; w1 = (w1 == rc) ? gg : w1;
              vv.w = w0 | (w1 << 16);
              if (hit) root4[c] = vv;
            }
          }
          if (rd == rcX) rd = g;
        }
      }
    }
  };

  unsigned short D0 = onbr[lane], D1 = onbr[64 + lane],
                 D2 = onbr[128 + lane], D3 = onbr[192 + lane];
  for (int b = 0; b < NPTS / 16; ++b) {
    unsigned short N0 = 0, N1 = 0, N2 = 0, N3 = 0;
    if (b + 1 < NPTS / 16) {
      const int nb = (b + 1) * 256 + lane;
      N0 = onbr[nb]; N1 = onbr[nb + 64]; N2 = onbr[nb + 128]; N3 = onbr[nb + 192];
    }
    const int p0 = (int)rootR[D0 & 0x1FFF];
    const int p1 = (int)rootR[D1 & 0x1FFF];
    const int p2 = (int)rootR[D2 & 0x1FFF];
    const int p3 = (int)rootR[D3 & 0x1FFF];
    bool cln = true;
    const int base = b << 4;
    process(D0, p0, base, cln);
    process(D1, p1, base + 4, cln);
    process(D2, p2, base + 8, cln);
    process(D3, p3, base + 12, cln);
    D0 = N0; D1 = N1; D2 = N2; D3 = N3;
  }
  if (lane == 0) death[orderS[0]] = scali[0];  // essential pair
}

// ---------------- loss (1024 threads): top-10 persistence via LDS-staged pers ----------------
__global__ __launch_bounds__(1024) void loss_kernel(const float* __restrict__ kde,
                                                    const int* __restrict__ death,
                                                    float* __restrict__ out) {
  __shared__ float persS[NPTS];  // 32 KB
  __shared__ float redv[1024];
  __shared__ int redi[1024];
  const int t = threadIdx.x;
  for (int p = t; p < NPTS; p += 1024) {
    int d = death[p];
    persS[p] = (d < 0) ? -__builtin_inff() : kde[p] - kde[d];
  }
  __syncthreads();
  int chosen[DESTNUM];
  for (int k = 0; k < DESTNUM; ++k) {
    float bv = -__builtin_inff();
    int bi = 1 << 30;
    for (int p = t; p < NPTS; p += 1024) {
      float pv = persS[p];
      if (pv > bv || (pv == bv && p < bi)) { bv = pv; bi = p; }
    }
    redv[t] = bv; redi[t] = bi;
    __syncthreads();
    for (int s = 512; s; s >>= 1) {
      if (t < s) {
        if (redv[t + s] > redv[t] || (redv[t + s] == redv[t] && redi[t + s] < redi[t])) {
          redv[t] = redv[t + s];
          redi[t] = redi[t + s];
        }
      }
      __syncthreads();
    }
    chosen[k] = redi[0];
    if (t == 0 && redi[0] < NPTS) persS[redi[0]] = -__builtin_inff();
    __syncthreads();
  }
  float acc = 0.f;
  for (int p = t; p < NPTS; p += 1024) {
    int d = death[p];
    if (d < 0) continue;
    bool sal = false;
    for (int c = 0; c < DESTNUM; ++c) sal |= (chosen[c] == p);
    float dv = kde[d];
    float kp = kde[p];
    acc += sal ? ((kp - 1.f) * (kp - 1.f) + dv * dv) : (kp - dv) * (kp - dv);
  }
  redv[t] = acc;
  __syncthreads();
  for (int s = 512; s; s >>= 1) {
    if (t < s) redv[t] += redv[t + s];
    __syncthreads();
  }
  if (t == 0) out[0] = redv[0];
}

extern "C" void kernel_launch(void* const* d_in, const int* in_sizes, int n_in,
                              void* d_out, int out_size, void* d_ws, size_t ws_size,
                              hipStream_t stream) {
  const unsigned short* x = (const unsigned short*)d_in[0];

  float* xT = (float*)d_ws;                       // NPTS*DIM f32 transposed (1 MB)
  float* kde = xT + NPTS * DIM;                   // NPTS f32
  int* scali = (int*)(kde + NPTS);                // [0] = argmin idx
  int* flag = scali + 64;                         // [0] = dtype flag (1=bf16, 0=f32)
  int* order = flag + 64;                         // NPTS (16B-aligned for int4 loads)
  int* rankp = order + NPTS;                      // NPTS
  int* rips = rankp + NPTS;                       // NPTS*KRIPS
  unsigned short* onbr = (unsigned short*)(rips + NPTS * KRIPS);  // NPTS*KRIPS u16
  int* death = (int*)(onbr + NPTS * KRIPS);       // NPTS

  hipLaunchKernelGGL(detect_kernel, dim3(1), dim3(64), 0, stream, x, flag);
  hipLaunchKernelGGL(tr_kernel, dim3(NPTS * DIM / 256), dim3(256), 0, stream, x, flag, xT);
  hipLaunchKernelGGL(knn2_kernel, dim3(NPTS / 2), dim3(256), 0, stream, xT, kde, rips);
  hipLaunchKernelGGL(prep_kernel, dim3(1), dim3(1024), 0, stream, kde, death, scali);
  hipLaunchKernelGGL(sort_kernel, dim3(1), dim3(1024), 0, stream, kde, order, rankp);
  hipLaunchKernelGGL(onbr_kernel, dim3(NPTS * KRIPS / 256), dim3(256), 0, stream,
                     order, rankp, rips, onbr);
  hipLaunchKernelGGL(scan_kernel, dim3(1), dim3(64), 0, stream, order, onbr, death, scali);
  hipLaunchKernelGGL(loss_kernel, dim3(1), dim3(1024), 0, stream, kde, death, (float*)d_out);
}

// Round 13
// 801.513 us; speedup vs baseline: 1.1045x; 1.1045x over previous
//
#include <hip/hip_runtime.h>
#include <hip/hip_bf16.h>

#define NPTS 8192
#define DIM 32
#define KKDE 32
#define KRIPS 16
#define DESTNUM 10

__device__ __forceinline__ unsigned long long shfl_xor_u64(unsigned long long v, int m) {
  int lo = __shfl_xor((int)(unsigned)(v & 0xFFFFFFFFull), m, 64);
  int hi = __shfl_xor((int)(unsigned)(v >> 32), m, 64);
  return (((unsigned long long)(unsigned)hi) << 32) | (unsigned)lo;
}

// DPP row (16-lane) rotate-based reductions: VALU-speed.
template <int CTRL>
__device__ __forceinline__ int dpp_mov(int v) {
  return __builtin_amdgcn_update_dpp(0, v, CTRL, 0xF, 0xF, false);
}
__device__ __forceinline__ int row_max16(int v) {
  int t;
  t = dpp_mov<0x128>(v); v = (t > v) ? t : v;  // row_ror:8
  t = dpp_mov<0x124>(v); v = (t > v) ? t : v;  // row_ror:4
  t = dpp_mov<0x122>(v); v = (t > v) ? t : v;  // row_ror:2
  t = dpp_mov<0x121>(v); v = (t > v) ? t : v;  // row_ror:1
  return v;
}
__device__ __forceinline__ int row_min16(int v) {
  int t;
  t = dpp_mov<0x128>(v); v = (t < v) ? t : v;
  t = dpp_mov<0x124>(v); v = (t < v) ? t : v;
  t = dpp_mov<0x122>(v); v = (t < v) ? t : v;
  t = dpp_mov<0x121>(v); v = (t < v) ? t : v;
  return v;
}
// 64-lane sum: DPP row-sum then 4 readlanes (uniform result, no ds_swizzle chain)
__device__ __forceinline__ int wave_sum64(int c) {
  int t;
  t = dpp_mov<0x128>(c); c += t;
  t = dpp_mov<0x124>(c); c += t;
  t = dpp_mov<0x122>(c); c += t;
  t = dpp_mov<0x121>(c); c += t;
  return __builtin_amdgcn_readlane(c, 0) + __builtin_amdgcn_readlane(c, 16) +
         __builtin_amdgcn_readlane(c, 32) + __builtin_amdgcn_readlane(c, 48);
}

// ---------------- dtype detector: is x bf16-packed or f32? ----------------
__global__ __launch_bounds__(64) void detect_kernel(const unsigned short* __restrict__ x,
                                                    int* __restrict__ flag) {
  int lane = threadIdx.x;
  unsigned u = x[2 * lane];
  int e = (u >> 7) & 0xFF;
  bool pass = (e >= 110 && e <= 130);
  unsigned long long b = __ballot(pass);
  if (lane == 0) flag[0] = (__popcll(b) >= 32) ? 1 : 0;
}

// ---------------- transpose: xT[q][p] = x[p][q] as f32 (exact) ----------------
__global__ __launch_bounds__(256) void tr_kernel(const unsigned short* __restrict__ xh,
                                                 const int* __restrict__ flag,
                                                 float* __restrict__ xT) {
  int e = blockIdx.x * 256 + threadIdx.x;  // < NPTS*DIM
  if (e >= NPTS * DIM) return;
  int p = e >> 5, q = e & 31;
  float v;
  if (flag[0] != 0) v = __uint_as_float(((unsigned)xh[e]) << 16);
  else v = ((const float*)xh)[e];
  xT[q * NPTS + p] = v;
}

// ---------------- shared register-resident per-wave top-K selection ----------------
// v8: data-seeded bisection bracket (R9-proven). Output bit-identical for any
// final hi with count in [32,64] (candidates superset of true top-32).
__device__ __forceinline__ void topk_emit(const unsigned* K, const int i, const int w,
                                          const int lane, const int t,
                                          unsigned long long* cand, unsigned long long* srt,
                                          unsigned long long* fin, float* knnv, int* knni,
                                          float* __restrict__ kde, int* __restrict__ rips) {
  unsigned lmin = K[0];
#pragma unroll
  for (int e = 1; e < 32; ++e) lmin = (K[e] < lmin) ? K[e] : lmin;
  // all values < 0x80000000 -> int compare == uint compare
  const int rmn = row_min16((int)lmin);
  const int rmx = row_max16((int)lmin);
  int gmn = __builtin_amdgcn_readlane(rmn, 0);
  int a16 = __builtin_amdgcn_readlane(rmn, 16); gmn = (a16 < gmn) ? a16 : gmn;
  int a32 = __builtin_amdgcn_readlane(rmn, 32); gmn = (a32 < gmn) ? a32 : gmn;
  int a48 = __builtin_amdgcn_readlane(rmn, 48); gmn = (a48 < gmn) ? a48 : gmn;
  int gmx = __builtin_amdgcn_readlane(rmx, 0);
  int b16 = __builtin_amdgcn_readlane(rmx, 16); gmx = (b16 > gmx) ? b16 : gmx;
  int b32 = __builtin_amdgcn_readlane(rmx, 32); gmx = (b32 > gmx) ? b32 : gmx;
  int b48 = __builtin_amdgcn_readlane(rmx, 48); gmx = (b48 > gmx) ? b48 : gmx;
  unsigned lo = (gmn == 0) ? 0u : (unsigned)gmn - 1u;
  unsigned hi = (unsigned)gmx;
  int chi = 2048;
  while (chi > 64 && (hi - lo) > 3u) {
    const unsigned span = hi - lo;
    const unsigned t1 = lo + (span >> 2);
    const unsigned t2 = lo + (span >> 1);
    int c = 0;
#pragma unroll
    for (int e = 0; e < 32; ++e) {
      unsigned a = (K[e] <= t2) ? 0x10000u : 0u;
      a = (K[e] <= t1) ? 0x10001u : a;
      c += (int)a;
    }
    const int tot = wave_sum64(c);
    const int c1 = tot & 0xFFFF;
    const int c2 = (int)((unsigned)tot >> 16);
    if (c1 >= 32) { hi = t1; chi = c1; }
    else if (c2 >= 32) { lo = t1; hi = t2; chi = c2; }
    else lo = t2;
  }
  while (chi > 64 && (hi - lo) > 1u) {  // exact tail (pathological ties only)
    const unsigned mid = lo + ((hi - lo) >> 1);
    int c = 0;
#pragma unroll
    for (int e = 0; e < 32; ++e) c += (K[e] <= mid) ? 1 : 0;
    const int tot = wave_sum64(c);
    if (tot >= 32) { hi = mid; chi = tot; } else lo = mid;
  }
  // deterministic extraction: ballot + prefix popcount
  cand[(w << 6) | lane] = ~0ull;
  const unsigned long long below = (lane == 0) ? 0ull : (~0ull >> (64 - lane));
  int base = 0;
#pragma unroll
  for (int e = 0; e < 32; ++e) {
    const bool sel = (K[e] <= hi);
    const unsigned long long b = __ballot(sel);
    if (sel) {
      const int pos = base + __popcll(b & below);
      if (pos < 64) {
        const int col = ((((w << 9) + ((e >> 2) << 6) + lane)) << 2) + (e & 3);
        cand[(w << 6) + pos] = (((unsigned long long)K[e]) << 32) | (unsigned)col;
      }
    }
    base += __popcll(b);
  }
  // per-wave bitonic sort of 64 candidates (v5 verbatim)
  unsigned long long v = cand[(w << 6) | lane];
#pragma unroll
  for (int k = 2; k <= 64; k <<= 1) {
#pragma unroll
    for (int j = 32; j > 0; j >>= 1) {
      if (j >= k) continue;
      unsigned long long o = shfl_xor_u64(v, j);
      bool keepMin = (((lane & k) == 0) == ((lane & j) == 0));
      v = keepMin ? (v < o ? v : o) : (v > o ? v : o);
    }
  }
  if (lane < 32) srt[(w << 5) | lane] = v;
  __syncthreads();
  if (w < 2) {
    const unsigned long long* A = &srt[(w * 2) << 5];
    const unsigned long long* B = &srt[(w * 2 + 1) << 5];
    unsigned long long m = (lane < 32) ? A[lane] : B[63 - lane];
#pragma unroll
    for (int j = 32; j > 0; j >>= 1) {
      unsigned long long o = shfl_xor_u64(m, j);
      bool keepMin = ((lane & j) == 0);
      m = keepMin ? (m < o ? m : o) : (m > o ? m : o);
    }
    if (lane < 32) fin[(w << 5) | lane] = m;
  }
  __syncthreads();
  if (w == 0) {
    unsigned long long m = (lane < 32) ? fin[lane] : fin[32 + (63 - lane)];
#pragma unroll
    for (int j = 32; j > 0; j >>= 1) {
      unsigned long long o = shfl_xor_u64(m, j);
      bool keepMin = ((lane & j) == 0);
      m = keepMin ? (m < o ? m : o) : (m > o ? m : o);
    }
    if (lane < 32) {
      knnv[lane] = __uint_as_float((unsigned)(m >> 32));
      knni[lane] = (int)(m & 0x1FFFull);
    }
  }
  __syncthreads();
  if (t == 0) {
    float s = 0.f;
    for (int k = 0; k < KKDE; ++k) s += expf(knnv[k] * -0.015625f);  // exp(-d2/64), ascending
    kde[i] = s;
  }
  if (t < KRIPS) rips[i * KRIPS + t] = knni[t];
}

// ---------------- dist: 128x128 register-blocked tile of D = |xi-xj|^2 ----------------
__global__ __launch_bounds__(256) void dist_kernel(const float* __restrict__ xT,
                                                   float* __restrict__ Dc,
                                                   int c0) {
  __shared__ float ax[DIM][128];
  __shared__ float bx[DIM][128];
  __shared__ float sqS[128];
  __shared__ float sS[128];
  const int t = threadIdx.x;
  const int i0 = c0 + blockIdx.y * 128;
  const int j0 = blockIdx.x * 128;
  for (int e = t; e < DIM * 128; e += 256) {
    int q = e >> 7, l = e & 127;
    ax[q][l] = xT[q * NPTS + i0 + l];
    bx[q][l] = xT[q * NPTS + j0 + l];
  }
  __syncthreads();
  {
    const int l = t & 127;
    const float* col = (t < 128) ? &ax[0][l] : &bx[0][l];
    float s = 0.f;
#pragma unroll
    for (int q = 0; q < DIM; ++q) s = fmaf(col[q * 128], col[q * 128], s);
    if (t < 128) sqS[l] = s;
    else sS[l] = s;
  }
  __syncthreads();
  const int tr = (t >> 4) << 3;
  const int tc = (t & 15) << 3;
  float acc[8][8];
#pragma unroll
  for (int a = 0; a < 8; ++a)
#pragma unroll
    for (int b = 0; b < 8; ++b) acc[a][b] = 0.f;
#pragma unroll 4
  for (int q = 0; q < DIM; ++q) {
    float4 a0 = *(const float4*)&ax[q][tr];
    float4 a1 = *(const float4*)&ax[q][tr + 4];
    float4 b0 = *(const float4*)&bx[q][tc];
    float4 b1 = *(const float4*)&bx[q][tc + 4];
    float ar[8] = {a0.x, a0.y, a0.z, a0.w, a1.x, a1.y, a1.z, a1.w};
    float br[8] = {b0.x, b0.y, b0.z, b0.w, b1.x, b1.y, b1.z, b1.w};
#pragma unroll
    for (int a = 0; a < 8; ++a)
#pragma unroll
      for (int b = 0; b < 8; ++b) acc[a][b] = fmaf(ar[a], br[b], acc[a][b]);
  }
#pragma unroll
  for (int a = 0; a < 8; ++a) {
    const float sqi = sqS[tr + a];
    float4 o0, o1;
    o0.x = fmaxf(fmaf(-2.f, acc[a][0], sqi + sS[tc + 0]), 0.f);
    o0.y = fmaxf(fmaf(-2.f, acc[a][1], sqi + sS[tc + 1]), 0.f);
    o0.z = fmaxf(fmaf(-2.f, acc[a][2], sqi + sS[tc + 2]), 0.f);
    o0.w = fmaxf(fmaf(-2.f, acc[a][3], sqi + sS[tc + 3]), 0.f);
    o1.x = fmaxf(fmaf(-2.f, acc[a][4], sqi + sS[tc + 4]), 0.f);
    o1.y = fmaxf(fmaf(-2.f, acc[a][5], sqi + sS[tc + 5]), 0.f);
    o1.z = fmaxf(fmaf(-2.f, acc[a][6], sqi + sS[tc + 6]), 0.f);
    o1.w = fmaxf(fmaf(-2.f, acc[a][7], sqi + sS[tc + 7]), 0.f);
    float* dst = Dc + (size_t)(i0 - c0 + tr + a) * NPTS + (j0 + tc);
    *(float4*)dst = o0;
    *(float4*)(dst + 4) = o1;
  }
}

// ---------------- select v8: register-resident quarter straight from global D ----------------
__global__ __launch_bounds__(256) void select_kernel(const float* __restrict__ Dc,
                                                     float* __restrict__ kde,
                                                     int* __restrict__ rips,
                                                     int c0) {
  __shared__ unsigned long long cand[4 * 64];  // 2 KB
  __shared__ unsigned long long srt[4 * 32];   // 1 KB
  __shared__ unsigned long long fin[64];       // 512 B
  __shared__ float knnv[KKDE];
  __shared__ int knni[KKDE];
  const int i = c0 + blockIdx.x;
  const int t = threadIdx.x;
  const int w = t >> 6, lane = t & 63;
  const float4* D4 = (const float4*)(Dc + (size_t)blockIdx.x * NPTS);
  unsigned K[32];
#pragma unroll
  for (int s = 0; s < 8; ++s) {
    float4 v = D4[(w << 9) + (s << 6) + lane];
    K[4 * s + 0] = __float_as_uint(v.x);
    K[4 * s + 1] = __float_as_uint(v.y);
    K[4 * s + 2] = __float_as_uint(v.z);
    K[4 * s + 3] = __float_as_uint(v.w);
  }
  topk_emit(K, i, w, lane, t, cand, srt, fin, knnv, knni, kde, rips);
}

// ---------------- kNN v8 (fallback): fused compute-into-registers + selection ----------------
__global__ __launch_bounds__(256) void knn_kernel(const float* __restrict__ xT,
                                                  float* __restrict__ kde,
                                                  int* __restrict__ rips) {
  __shared__ unsigned long long cand[4 * 64];
  __shared__ unsigned long long srt[4 * 32];
  __shared__ unsigned long long fin[64];
  __shared__ float knnv[KKDE];
  __shared__ int knni[KKDE];
  __shared__ float xis[DIM];
  const int i = blockIdx.x;
  const int t = threadIdx.x;
  const int w = t >> 6, lane = t & 63;
  if (t < DIM) xis[t] = xT[t * NPTS + i];
  __syncthreads();
  float xi[DIM];
#pragma unroll
  for (int q = 0; q < DIM; ++q) xi[q] = xis[q];
  float sqi = 0.f;
#pragma unroll
  for (int q = 0; q < DIM; ++q) sqi = fmaf(xi[q], xi[q], sqi);
  const float4* xT4 = (const float4*)xT;
  unsigned K[32];
#pragma unroll
  for (int s = 0; s < 8; ++s) {
    const int j4 = (w << 9) + (s << 6) + lane;
    float d0 = 0.f, d1 = 0.f, d2 = 0.f, d3 = 0.f;
    float s0 = 0.f, s1 = 0.f, s2 = 0.f, s3 = 0.f;
#pragma unroll
    for (int q = 0; q < DIM; ++q) {
      float4 v = xT4[q * (NPTS / 4) + j4];
      const float xq = xi[q];
      d0 = fmaf(xq, v.x, d0); s0 = fmaf(v.x, v.x, s0);
      d1 = fmaf(xq, v.y, d1); s1 = fmaf(v.y, v.y, s1);
      d2 = fmaf(xq, v.z, d2); s2 = fmaf(v.z, v.z, s2);
      d3 = fmaf(xq, v.w, d3); s3 = fmaf(v.w, v.w, s3);
    }
    K[4 * s + 0] = __float_as_uint(fmaxf(fmaf(-2.f, d0, sqi + s0), 0.f));
    K[4 * s + 1] = __float_as_uint(fmaxf(fmaf(-2.f, d1, sqi + s1), 0.f));
    K[4 * s + 2] = __float_as_uint(fmaxf(fmaf(-2.f, d2, sqi + s2), 0.f));
    K[4 * s + 3] = __float_as_uint(fmaxf(fmaf(-2.f, d3, sqi + s3), 0.f));
  }
  topk_emit(K, i, w, lane, t, cand, srt, fin, knnv, knni, kde, rips);
}

// ---------------- prep (1024 threads): fused max + normalize + death-init + argmin ----------------
__global__ __launch_bounds__(1024) void prep_kernel(float* __restrict__ kde,
                                                    int* __restrict__ death,
                                                    int* __restrict__ scali) {
  __shared__ float red[1024];
  __shared__ unsigned long long red64[1024];
  __shared__ float kmaxS;
  const int t = threadIdx.x;
  float m = 0.f;
  for (int p = t; p < NPTS; p += 1024) m = fmaxf(m, kde[p]);
  red[t] = m;
  __syncthreads();
  for (int s = 512; s; s >>= 1) {
    if (t < s) red[t] = fmaxf(red[t], red[t + s]);
    __syncthreads();
  }
  if (t == 0) kmaxS = red[0];
  __syncthreads();
  const float km = kmaxS;
  unsigned long long best = ~0ull;
  for (int p = t; p < NPTS; p += 1024) {
    float v = kde[p] / km;
    kde[p] = v;
    death[p] = -1;
    unsigned long long kk = (((unsigned long long)__float_as_uint(v)) << 32) | (unsigned)p;
    if (kk < best) best = kk;
  }
  red64[t] = best;
  __syncthreads();
  for (int s = 512; s; s >>= 1) {
    if (t < s && red64[t + s] < red64[t]) red64[t] = red64[t + s];
    __syncthreads();
  }
  if (t == 0) scali[0] = (int)(red64[0] & 0xFFFFFFFFull);
}

// ---------------- bitonic sort (1024 threads: R6-proven big win) ----------------
__global__ __launch_bounds__(1024) void sort_kernel(const float* __restrict__ kde,
                                                    int* __restrict__ order,
                                                    int* __restrict__ rankp) {
  __shared__ float kv[NPTS];            // 32 KB
  __shared__ unsigned short ki[NPTS];   // 16 KB
  int t = threadIdx.x;
  for (int p = t; p < NPTS; p += 1024) { kv[p] = kde[p]; ki[p] = (unsigned short)p; }
  __syncthreads();
  for (int size = 2; size <= NPTS; size <<= 1) {
    for (int stride = size >> 1; stride > 0; stride >>= 1) {
      for (int q = t; q < NPTS / 2; q += 1024) {
        int lo = ((q & ~(stride - 1)) << 1) | (q & (stride - 1));
        int hi = lo + stride;
        float va = kv[lo], vb = kv[hi];
        int ia = ki[lo], ib = ki[hi];
        bool aFirst = (va > vb) || (va == vb && ia < ib);
        bool up = ((lo & size) == 0);
        if (up != aFirst) {
          kv[lo] = vb; kv[hi] = va;
          ki[lo] = (unsigned short)ib; ki[hi] = (unsigned short)ia;
        }
      }
      __syncthreads();
    }
  }
  for (int p = t; p < NPTS; p += 1024) {
    int idx = ki[p];
    order[p] = idx;
    rankp[idx] = p;
  }
}

// ---------------- ordered neighbor stream (flat: [t*16 + kk]) ----------------
__global__ __launch_bounds__(256) void onbr_kernel(const int* __restrict__ order,
                                                   const int* __restrict__ rankp,
                                                   const int* __restrict__ rips,
                                                   unsigned short* __restrict__ onbr) {
  int e = blockIdx.x * 256 + threadIdx.x;  // e < NPTS*KRIPS
  if (e >= NPTS * KRIPS) return;
  int t = e >> 4, kk = e & 15;
  int i = order[t];
  int nbr = rips[i * KRIPS + kk];
  int r = rankp[nbr];
  unsigned short v = (unsigned short)r;
  if (r < t) {  // self has rank == t -> invalid, matching ref
    v |= 0x8000;
    if ((r >> 4) == (t >> 4)) v |= 0x4000;  // hazard: same prefetch window
  }
  onbr[e] = v;
}

// ---------------- persistence scan (R7 version, 426us best measured) ----------------
__global__ __launch_bounds__(64) void scan_kernel(const int* __restrict__ order,
                                                  const unsigned short* __restrict__ onbr,
                                                  int* __restrict__ death,
                                                  const int* __restrict__ scali) {
  __shared__ __align__(16) unsigned short rootR[NPTS];   // 16 KB, rank -> root rank
  __shared__ unsigned short orderS[NPTS];                // 16 KB, rank -> point id
  const int lane = threadIdx.x;
  for (int p = lane; p < NPTS; p += 64) {
    rootR[p] = (unsigned short)p;
    orderS[p] = (unsigned short)order[p];
  }
  __syncthreads();
  const int sub = lane >> 4;  // subgroup = DPP row = one position per call

  auto process = [&](unsigned short D, int pref, int posBase, bool& cln) {
    const int nbr = D & 0x1FFF;
    const bool valid = (D & 0x8000) != 0;
    const bool hz = (D & 0x4000) != 0;
    int rd = cln ? pref : (int)rootR[nbr];
    const int rv = row_max16(valid ? rd : -1);
    const bool uniOk = !valid || (rd == rv);
    const unsigned long long uniB = __ballot(uniOk);
    const unsigned long long hzB = __ballot(hz);
    const unsigned long long badB = (~uniB) | hzB;
    if (badB == 0ull) {  // all 4 rows uniform, no hazards: pure attach
      if ((lane & 15) == 0 && rv >= 0) rootR[posBase + sub] = (unsigned short)rv;
      return;
    }
    const int sstar = (__ffsll(badB) - 1) >> 4;  // first dirty row
    // rows < sstar are hazard-free & uniform: commit their attaches now
    if ((lane & 15) == 0 && sub < sstar && rv >= 0)
      rootR[posBase + sub] = (unsigned short)rv;
    cln = false;
    // hazard lanes may hold stale values; re-read them AFTER the commits above.
    if (hzB != 0ull) {
      const int f = (int)rootR[nbr];
      rd = hz ? f : rd;
    }
    // ---- exit ramp: hazard-patched batch that is still a pure attach ----
    {
      const bool fwd2 = hz && (nbr >= posBase + sstar);  // target not committed yet
      const int rv2 = row_max16(valid ? rd : -1);
      const unsigned long long bad2 = __ballot(fwd2 || (valid && rd != rv2));
      if (bad2 == 0ull) {
        if ((lane & 15) == 0 && sub >= sstar && rv2 >= 0)
          rootR[posBase + sub] = (unsigned short)rv2;
        return;
      }
    }
    const unsigned long long vbAll = __ballot(valid);
    for (int s = sstar; s < 4; ++s) {
      const int pos = posBase + s;
      const unsigned long long smask = 0xFFFFull << (s << 4);
      const unsigned long long vb = vbAll & smask;
      if (vb == 0ull) continue;  // birth: rootR[pos] stays pos
      const int cl = __ffsll(vb) - 1;
      const int gc = __builtin_amdgcn_readlane(rd, cl);
      const unsigned long long uni2 = __ballot(!valid || rd == gc);
      if ((uni2 & smask) == smask) {  // all valid roots equal: attach
        if (lane == (s << 4)) rootR[pos] = (unsigned short)gc;
        if (nbr == pos) rd = gc;
      } else {                        // merge: winner = min rank (densest)
        const int g = __builtin_amdgcn_readlane(row_min16(valid ? rd : 0x7FFFFFFF), s << 4);
        const bool dy = (sub == s) && valid && (rd != g);
        if (dy) {
          const int pid = orderS[rd];
          rootR[rd] = (unsigned short)g;
          death[pid] = (int)orderS[pos];
        }
        if (lane == (s << 4)) rootR[pos] = (unsigned short)g;
        unsigned long long db = __ballot(dy);
        if (nbr == pos) rd = g;
        while (db != 0ull) {
          const int dl = __ffsll(db) - 1;
          const int rcX = __builtin_amdgcn_readlane(rd, dl);
          db &= ~__ballot(rd == rcX);
          // members of rcX all lie in (rcX, pos): 8x-wide span relabel.
          {
            const int c0 = (rcX + 1) >> 3;   // first uint4 chunk (8 u16 each)
            const int c1 = (pos + 7) >> 3;   // exclusive
            uint4* root4 = (uint4*)rootR;
            const unsigned rc = (unsigned)rcX;
            const unsigned gg = (unsigned)g;
            for (int c = c0 + lane; c < c1; c += 64) {
              uint4 vv = root4[c];
              unsigned w0, w1;
              bool hit = false;
              w0 = vv.x & 0xFFFFu; w1 = vv.x >> 16;
              hit |= (w0 == rc) | (w1 == rc);
              w0 = (w0 == rc) ? gg : w0; w1 = (w1 == rc) ? gg : w1;
              vv.x = w0 | (w1 << 16);
              w0 = vv.y & 0xFFFFu; w1 = vv.y >> 16;
              hit |= (w0 == rc) | (w1 == rc);
              w0 = (w0 == rc) ? gg : w0; w1 = (w1 == rc) ? gg : w1;
              vv.y = w0 | (w1 << 16);
              w0 = vv.z & 0xFFFFu; w1 = vv.z >> 16;
              hit |= (w0 == rc) | (w1 == rc);
              w0 = (w0 == rc) ? gg : w0; w1 = (w1 == rc) ? gg : w1;
              vv.z = w0 | (w1 << 16);
              w0 = vv.w & 0xFFFFu; w1 = vv.w >> 16;
              hit |= (w0 == rc) | (w1 == rc);
              w0 = (w0 == rc) ? gg : w0; w1 = (w1 == rc) ? gg : w1;
              vv.w = w0 | (w1 << 16);
              if (hit) root4[c] = vv;
            }
          }
          if (rd == rcX) rd = g;
        }
      }
    }
  };

  unsigned short D0 = onbr[lane], D1 = onbr[64 + lane],
                 D2 = onbr[128 + lane], D3 = onbr[192 + lane];
  for (int b = 0; b < NPTS / 16; ++b) {
    unsigned short N0 = 0, N1 = 0, N2 = 0, N3 = 0;
    if (b + 1 < NPTS / 16) {
      const int nb = (b + 1) * 256 + lane;
      N0 = onbr[nb]; N1 = onbr[nb + 64]; N2 = onbr[nb + 128]; N3 = onbr[nb + 192];
    }
    const int p0 = (int)rootR[D0 & 0x1FFF];
    const int p1 = (int)rootR[D1 & 0x1FFF];
    const int p2 = (int)rootR[D2 & 0x1FFF];
    const int p3 = (int)rootR[D3 & 0x1FFF];
    bool cln = true;
    const int base = b << 4;
    process(D0, p0, base, cln);
    process(D1, p1, base + 4, cln);
    process(D2, p2, base + 8, cln);
    process(D3, p3, base + 12, cln);
    D0 = N0; D1 = N1; D2 = N2; D3 = N3;
  }
  if (lane == 0) death[orderS[0]] = scali[0];  // essential pair
}

// ---------------- loss (1024 threads): top-10 persistence via LDS-staged pers ----------------
__global__ __launch_bounds__(1024) void loss_kernel(const float* __restrict__ kde,
                                                    const int* __restrict__ death,
                                                    float* __restrict__ out) {
  __shared__ float persS[NPTS];  // 32 KB
  __shared__ float redv[1024];
  __shared__ int redi[1024];
  const int t = threadIdx.x;
  for (int p = t; p < NPTS; p += 1024) {
    int d = death[p];
    persS[p] = (d < 0) ? -__builtin_inff() : kde[p] - kde[d];
  }
  __syncthreads();
  int chosen[DESTNUM];
  for (int k = 0; k < DESTNUM; ++k) {
    float bv = -__builtin_inff();
    int bi = 1 << 30;
    for (int p = t; p < NPTS; p += 1024) {
      float pv = persS[p];
      if (pv > bv || (pv == bv && p < bi)) { bv = pv; bi = p; }
    }
    redv[t] = bv; redi[t] = bi;
    __syncthreads();
    for (int s = 512; s; s >>= 1) {
      if (t < s) {
        if (redv[t + s] > redv[t] || (redv[t + s] == redv[t] && redi[t + s] < redi[t])) {
          redv[t] = redv[t + s];
          redi[t] = redi[t + s];
        }
      }
      __syncthreads();
    }
    chosen[k] = redi[0];
    if (t == 0 && redi[0] < NPTS) persS[redi[0]] = -__builtin_inff();
    __syncthreads();
  }
  float acc = 0.f;
  for (int p = t; p < NPTS; p += 1024) {
    int d = death[p];
    if (d < 0) continue;
    bool sal = false;
    for (int c = 0; c < DESTNUM; ++c) sal |= (chosen[c] == p);
    float dv = kde[d];
    float kp = kde[p];
    acc += sal ? ((kp - 1.f) * (kp - 1.f) + dv * dv) : (kp - dv) * (kp - dv);
  }
  redv[t] = acc;
  __syncthreads();
  for (int s = 512; s; s >>= 1) {
    if (t < s) redv[t] += redv[t + s];
    __syncthreads();
  }
  if (t == 0) out[0] = redv[0];
}

extern "C" void kernel_launch(void* const* d_in, const int* in_sizes, int n_in,
                              void* d_out, int out_size, void* d_ws, size_t ws_size,
                              hipStream_t stream) {
  const unsigned short* x = (const unsigned short*)d_in[0];

  float* xT = (float*)d_ws;                       // NPTS*DIM f32 transposed (1 MB)
  float* kde = xT + NPTS * DIM;                   // NPTS f32
  int* scali = (int*)(kde + NPTS);                // [0] = argmin idx
  int* flag = scali + 64;                         // [0] = dtype flag (1=bf16, 0=f32)
  int* order = flag + 64;                         // NPTS (16B-aligned for int4 loads)
  int* rankp = order + NPTS;                      // NPTS
  int* rips = rankp + NPTS;                       // NPTS*KRIPS
  unsigned short* onbr = (unsigned short*)(rips + NPTS * KRIPS);  // NPTS*KRIPS u16
  int* death = (int*)(onbr + NPTS * KRIPS);       // NPTS

  // D-chunk region after the fixed allocations, 1 KB aligned
  size_t baseBytes = (size_t)((char*)(death + NPTS) - (char*)d_ws);
  baseBytes = (baseBytes + 1023) & ~(size_t)1023;
  float* Dc = (float*)((char*)d_ws + baseBytes);
  size_t avail = (ws_size > baseBytes) ? (ws_size - baseBytes) : 0;
  const size_t rowB = (size_t)NPTS * 4;  // 32 KB per D row
  int CH = 0;
  for (int c = NPTS; c >= 1024; c >>= 1)
    if (avail >= (size_t)c * rowB) { CH = c; break; }

  hipLaunchKernelGGL(detect_kernel, dim3(1), dim3(64), 0, stream, x, flag);
  hipLaunchKernelGGL(tr_kernel, dim3(NPTS * DIM / 256), dim3(256), 0, stream, x, flag, xT);
  if (CH > 0) {
    for (int c0 = 0; c0 < NPTS; c0 += CH) {
      hipLaunchKernelGGL(dist_kernel, dim3(NPTS / 128, CH / 128), dim3(256), 0, stream,
                         xT, Dc, c0);
      hipLaunchKernelGGL(select_kernel, dim3(CH), dim3(256), 0, stream, Dc, kde, rips, c0);
    }
  } else {
    hipLaunchKernelGGL(knn_kernel, dim3(NPTS), dim3(256), 0, stream, xT, kde, rips);
  }
  hipLaunchKernelGGL(prep_kernel, dim3(1), dim3(1024), 0, stream, kde, death, scali);
  hipLaunchKernelGGL(sort_kernel, dim3(1), dim3(1024), 0, stream, kde, order, rankp);
  hipLaunchKernelGGL(onbr_kernel, dim3(NPTS * KRIPS / 256), dim3(256), 0, stream,
                     order, rankp, rips, onbr);
  hipLaunchKernelGGL(scan_kernel, dim3(1), dim3(64), 0, stream, order, onbr, death, scali);
  hipLaunchKernelGGL(loss_kernel, dim3(1), dim3(1024), 0, stream, kde, death, (float*)d_out);
}